// Round 4
// baseline (562.449 us; speedup 1.0000x reference)
//
#include <hip/hip_runtime.h>

// Gridding: B batches of N float3 points -> per-batch 64^3 grid of trilinear
// scatter weights.
//
// R4: R3 was divergence-bound: every wave executed the full scatter body with
// ~8/64 lanes active (P(no lane in slab) = (7/8)^64 ~ 0). Split into cheap
// filter + ballot/mbcnt compaction into a wave-private LDS queue, draining 64
// dense points at a time (100% lane utilization in the expensive body).
// Slab k owns planes [8k,8k+7] exactly: a point's lower-x corners are applied
// by the slab containing ix, upper-x corners by the slab containing ix+1
// (wx0/wx1 masked at the +-1 edges). Full d_out coverage by plain stores ->
// no boundary spill, no merge kernel, no memset: ONE dispatch.
// LDS: 128 KB grid + 16 waves * 128 * 12 B queue = 152 KB (<=160 KB).

#define GS    64
#define G2    (GS * GS)          // 4096
#define G3    (GS * GS * GS)     // 262144
#define SHALF 32                 // scale (half-extent); grid = 2*SHALF
#define TPB   1024
#define TH    8                  // planes per slab
#define NSLAB (GS / TH)          // 8
#define QCAP  128                // per-wave queue capacity (63 residual + 64 push)
#define NWAVE (TPB / 64)         // 16

__device__ __forceinline__ int prefix_count(unsigned long long m) {
    int c = __builtin_amdgcn_mbcnt_lo((unsigned)m, 0);
    return __builtin_amdgcn_mbcnt_hi((unsigned)(m >> 32), c);
}

// dense trilinear scatter of one already-scaled point into slab k's 8 planes
__device__ __forceinline__ void scatter_body(float x, float y, float z, int k,
                                             float* __restrict__ lg) {
    float lx = floorf(x), ly = floorf(y), lz = floorf(z);
    float fx = x - lx, fy = y - ly, fz = z - lz;
    int ix = min(max((int)lx + SHALF, 0), GS - 2);
    int iy = min(max((int)ly + SHALF, 0), GS - 2);
    int iz = min(max((int)lz + SHALF, 0), GS - 2);

    int rel = ix - TH * k;                   // in [-1, TH-1] for accepted pts
    float wx0 = (1.0f - fx) * ((rel >= 0)      ? 1.0f : 0.0f);  // lower corners
    float wx1 = fx          * ((rel <= TH - 2) ? 1.0f : 0.0f);  // upper corners
    int plo = max(rel, 0)          * G2 + iy * GS + iz;
    int phi = min(rel + 1, TH - 1) * G2 + iy * GS + iz;

    float wy0 = 1.0f - fy, wy1 = fy;
    float wz0 = 1.0f - fz, wz1 = fz;

    float a00 = wx0 * wy0, a01 = wx0 * wy1;
    float b00 = wx1 * wy0, b01 = wx1 * wy1;

    atomicAdd(&lg[plo],          a00 * wz0);
    atomicAdd(&lg[plo + 1],      a00 * wz1);
    atomicAdd(&lg[plo + GS],     a01 * wz0);
    atomicAdd(&lg[plo + GS + 1], a01 * wz1);
    atomicAdd(&lg[phi],          b00 * wz0);
    atomicAdd(&lg[phi + 1],      b00 * wz1);
    atomicAdd(&lg[phi + GS],     b01 * wz0);
    atomicAdd(&lg[phi + GS + 1], b01 * wz1);
}

__device__ __forceinline__ void filter_push(
    float px, float py, float pz, int lo, int hi, int k, int lane,
    int& count, float2* __restrict__ myqxy, float* __restrict__ myqz,
    float* __restrict__ lg) {
    float x = px * (float)SHALF;
    float y = py * (float)SHALF;
    float z = pz * (float)SHALF;
    int ix = min(max((int)floorf(x) + SHALF, 0), GS - 2);
    // reference zeroes weights of sum==0 points -> equivalent to skipping
    bool take = (ix >= lo) && (ix <= hi) && ((x + y + z) != 0.0f);

    unsigned long long m = __ballot(take);
    int pos = count + prefix_count(m);
    if (take) {
        myqxy[pos] = make_float2(x, y);
        myqz[pos]  = z;
    }
    count += __popcll(m);

    if (count >= 64) {              // wave-uniform branch
        count -= 64;
        int e = count + lane;       // stack drain: pop the newest 64
        float2 xy = myqxy[e];
        float  zz = myqz[e];
        scatter_body(xy.x, xy.y, zz, k, lg);
    }
}

__global__ __launch_bounds__(TPB, 1) void gridding_queue_kernel(
    const float* __restrict__ pt, float* __restrict__ out, int N) {
    __shared__ float  lg[TH * G2];           // 131072 B
    __shared__ float2 qxy[NWAVE * QCAP];     //  16384 B
    __shared__ float  qz [NWAVE * QCAP];     //   8192 B

    const int b    = blockIdx.x;    // batch  (flat%8 == b%8 -> XCD-affine)
    const int k    = blockIdx.y;    // slab
    const int tid  = threadIdx.x;
    const int lane = tid & 63;
    const int wv   = tid >> 6;
    float2* myqxy = qxy + wv * QCAP;
    float*  myqz  = qz  + wv * QCAP;

    float4* lg4 = (float4*)lg;
    for (int t = tid; t < TH * G2 / 4; t += TPB)
        lg4[t] = make_float4(0.f, 0.f, 0.f, 0.f);
    __syncthreads();

    const int lo = TH * k - 1;      // accept ix in [8k-1, 8k+TH-1]
    const int hi = TH * k + TH - 1;
    int count = 0;

    const float*  p  = pt + (size_t)b * N * 3;
    const float4* p4 = (const float4*)p;
    const int nq    = N >> 2;       // 4-point quads
    const int niter = nq / TPB;     // uniform (fast path requires exact)

    int q = tid;
    float4 A = p4[3 * q + 0], Bv = p4[3 * q + 1], C = p4[3 * q + 2];
    for (int it = 0; it < niter; ++it) {
        int qn = q + TPB;
        float4 A2, B2, C2;
        if (it + 1 < niter) {       // software prefetch of next quad
            A2 = p4[3 * qn + 0]; B2 = p4[3 * qn + 1]; C2 = p4[3 * qn + 2];
        } else {
            A2 = B2 = C2 = make_float4(0.f, 0.f, 0.f, 0.f);
        }
        filter_push(A.x,  A.y,  A.z,  lo, hi, k, lane, count, myqxy, myqz, lg);
        filter_push(A.w,  Bv.x, Bv.y, lo, hi, k, lane, count, myqxy, myqz, lg);
        filter_push(Bv.z, Bv.w, C.x,  lo, hi, k, lane, count, myqxy, myqz, lg);
        filter_push(C.y,  C.z,  C.w,  lo, hi, k, lane, count, myqxy, myqz, lg);
        A = A2; Bv = B2; C = C2; q = qn;
    }

    // residual (< 64 entries at [0, count))
    if (lane < count) {
        float2 xy = myqxy[lane];
        float  zz = myqz[lane];
        scatter_body(xy.x, xy.y, zz, k, lg);
    }
    __syncthreads();

    // plain-store the 8 owned planes (each d_out cell owned by exactly one slab)
    float4* ob = (float4*)(out + (size_t)b * G3 + (size_t)(TH * k) * G2);
    for (int t = tid; t < TH * G2 / 4; t += TPB) ob[t] = lg4[t];
}

// ---- fallback (general shapes): R1 atomic kernel ----
__global__ void gridding_atomic_kernel(const float* __restrict__ pt,
                                       float* __restrict__ out, int P, int N) {
    int i = blockIdx.x * blockDim.x + threadIdx.x;
    if (i >= P) return;
    int b = i / N;
    float x = pt[3 * i + 0] * (float)SHALF;
    float y = pt[3 * i + 1] * (float)SHALF;
    float z = pt[3 * i + 2] * (float)SHALF;
    const float m = ((x + y + z) != 0.0f) ? 1.0f : 0.0f;
    float lx = floorf(x), ly = floorf(y), lz = floorf(z);
    float fx = x - lx, fy = y - ly, fz = z - lz;
    int ix = min(max((int)lx + SHALF, 0), GS - 2);
    int iy = min(max((int)ly + SHALF, 0), GS - 2);
    int iz = min(max((int)lz + SHALF, 0), GS - 2);
    float* base = out + (size_t)b * G3 + ((ix * GS + iy) * GS + iz);
    float wx0 = (1.0f - fx) * m, wx1 = fx * m;
    float w00 = wx0 * (1.0f - fy), w01 = wx0 * fy;
    float w10 = wx1 * (1.0f - fy), w11 = wx1 * fy;
    atomicAdd(base,               w00 * (1.0f - fz));
    atomicAdd(base + 1,           w00 * fz);
    atomicAdd(base + GS,          w01 * (1.0f - fz));
    atomicAdd(base + GS + 1,      w01 * fz);
    atomicAdd(base + G2,          w10 * (1.0f - fz));
    atomicAdd(base + G2 + 1,      w10 * fz);
    atomicAdd(base + G2 + GS,     w11 * (1.0f - fz));
    atomicAdd(base + G2 + GS + 1, w11 * fz);
}

extern "C" void kernel_launch(void* const* d_in, const int* in_sizes, int n_in,
                              void* d_out, int out_size, void* d_ws, size_t ws_size,
                              hipStream_t stream) {
    const float* pt  = (const float*)d_in[0];
    float*       out = (float*)d_out;

    const int P = in_sizes[0] / 3;       // total points (B*N)
    const int B = out_size / G3;         // 32
    const int N = (B > 0) ? P / B : 0;   // 262144

    const bool fast = (B > 0) && (out_size == B * G3) && (P == B * N) &&
                      (N % (4 * TPB) == 0);

    if (fast) {
        dim3 grid1(B, NSLAB);            // 256 wg = 1/CU; b%8 fixes the XCD
        gridding_queue_kernel<<<grid1, TPB, 0, stream>>>(pt, out, N);
    } else {
        hipMemsetAsync(d_out, 0, (size_t)out_size * sizeof(float), stream);
        gridding_atomic_kernel<<<(P + 255) / 256, 256, 0, stream>>>(pt, out, P, N);
    }
}